// Round 5
// baseline (325.773 us; speedup 1.0000x reference)
//
#include <hip/hip_runtime.h>
#include <hip/hip_bf16.h>

#define DM 1024
#define NH 16
#define DH 64
#define BB 4
#define SS 2048
#define MROWS (BB*SS)   // 8192

typedef unsigned short u16;
typedef short bf16x8 __attribute__((ext_vector_type(8)));
typedef short bf16x4 __attribute__((ext_vector_type(4)));
typedef float f32x4 __attribute__((ext_vector_type(4)));
typedef unsigned uintx2 __attribute__((ext_vector_type(2)));

#define MFMA16(a, b, c) __builtin_amdgcn_mfma_f32_16x16x32_bf16((a), (b), (c), 0, 0, 0)
#define MFMA16K16(a, b, c) __builtin_amdgcn_mfma_f32_16x16x16bf16_1k((a), (b), (c), 0, 0, 0)

__device__ __forceinline__ u16 f2bf(float f) {
  union { float f; unsigned u; } v; v.f = f;
  unsigned u = v.u;
  return (u16)((u + 0x7fffu + ((u >> 16) & 1u)) >> 16);
}

// pack two floats -> u32 of two RNE bf16 (lo = a, hi = b)
__device__ __forceinline__ unsigned pack2bf(float a, float b) {
  __hip_bfloat162 h = __float22bfloat162_rn(make_float2(a, b));
  unsigned u;
  __builtin_memcpy(&u, &h, 4);
  return u;
}

__device__ __forceinline__ bf16x8 ld_bf8(const u16* p) {
  return *(const bf16x8*)p;
}

// ---------------- convert x (fp32 -> bf16), 4 elems/thread ----------------
__global__ __launch_bounds__(256) void k_cvt_x(const float* __restrict__ x,
                                               u16* __restrict__ xb) {
  int i = (blockIdx.x * 256 + threadIdx.x) * 4;
  float4 v = *(const float4*)(x + i);
  ushort4 o;
  o.x = f2bf(v.x); o.y = f2bf(v.y); o.z = f2bf(v.z); o.w = f2bf(v.w);
  *(ushort4*)(xb + i) = o;
}

// ------------- transpose weights W[K,N] -> Wt[N,K] bf16, 4 segments -------
__global__ __launch_bounds__(1024) void k_tw(const float* __restrict__ Wq,
                                             const float* __restrict__ Wk,
                                             const float* __restrict__ Wv,
                                             const float* __restrict__ Wo,
                                             u16* __restrict__ Wt) {
  __shared__ float t[32][33];
  int k0 = blockIdx.x * 32;
  int seg = blockIdx.y >> 5;
  int n0 = (blockIdx.y & 31) * 32;
  const float* W = seg == 0 ? Wq : seg == 1 ? Wk : seg == 2 ? Wv : Wo;
  int tx = threadIdx.x, ty = threadIdx.y;
  t[ty][tx] = W[(size_t)(k0 + ty) * DM + n0 + tx];
  __syncthreads();
  Wt[(size_t)(seg * DM + n0 + ty) * DM + k0 + tx] = f2bf(t[tx][ty]);
}

// ---------------- GEMM: C[M,N] = A[M,K] * Bt[N,K]^T + bias ----------------
// (unchanged)
__global__ __launch_bounds__(256) void k_gemm(
    const u16* __restrict__ A, const u16* __restrict__ Bt,
    int M, int N, int K,
    const float* __restrict__ b0, const float* __restrict__ b1,
    const float* __restrict__ b2,
    u16* __restrict__ oq, u16* __restrict__ ok, u16* __restrict__ ov,
    float* __restrict__ of, int mode) {
  __shared__ __align__(16) u16 As[128 * 32];
  __shared__ __align__(16) u16 Bs[128 * 32];
  int tid = threadIdx.x;
  int wave = tid >> 6, lane = tid & 63, quad = lane >> 4, l16 = lane & 15;
  int bm = blockIdx.x * 128, bn = blockIdx.y * 128;
  int wr = (wave >> 1) * 64, wc = (wave & 1) * 64;
  f32x4 acc[4][4] = {};

  const u16* ga = A + (size_t)(bm + wave * 32 + (lane >> 2)) * K + (lane & 3) * 8;
  const u16* gb = Bt + (size_t)(bn + wave * 32 + (lane >> 2)) * K + (lane & 3) * 8;
  u16* lda = &As[wave * 1024];
  u16* ldb = &Bs[wave * 1024];

  for (int k0 = 0; k0 < K; k0 += 32) {
#pragma unroll
    for (int i = 0; i < 2; ++i) {
      __builtin_amdgcn_global_load_lds(
          (const __attribute__((address_space(1))) void*)(ga + (size_t)i * 16 * K + k0),
          (__attribute__((address_space(3))) void*)(lda + i * 512), 16, 0, 0);
      __builtin_amdgcn_global_load_lds(
          (const __attribute__((address_space(1))) void*)(gb + (size_t)i * 16 * K + k0),
          (__attribute__((address_space(3))) void*)(ldb + i * 512), 16, 0, 0);
    }
    __syncthreads();
    bf16x8 af[4], bfr[4];
#pragma unroll
    for (int mi = 0; mi < 4; ++mi)
      af[mi] = *(const bf16x8*)(&As[(wr + mi * 16 + l16) * 32 + quad * 8]);
#pragma unroll
    for (int ni = 0; ni < 4; ++ni)
      bfr[ni] = *(const bf16x8*)(&Bs[(wc + ni * 16 + l16) * 32 + quad * 8]);
#pragma unroll
    for (int mi = 0; mi < 4; ++mi)
#pragma unroll
      for (int ni = 0; ni < 4; ++ni)
        acc[mi][ni] = MFMA16(af[mi], bfr[ni], acc[mi][ni]);
    __syncthreads();
  }

  if (mode == 0) {
#pragma unroll
    for (int mi = 0; mi < 4; ++mi)
#pragma unroll
      for (int ni = 0; ni < 4; ++ni)
#pragma unroll
        for (int r = 0; r < 4; ++r) {
          int row = bm + wr + mi * 16 + quad * 4 + r;
          int col = bn + wc + ni * 16 + l16;
          of[(size_t)row * N + col] = acc[mi][ni][r] + b0[col];
        }
  } else {
    int seg = bn >> 10;
    const float* bia = seg == 0 ? b0 : seg == 1 ? b1 : b2;
    int cb = bn & 1023;
    if (seg == 2) {
#pragma unroll
      for (int mi = 0; mi < 4; ++mi)
#pragma unroll
        for (int ni = 0; ni < 4; ++ni) {
          int row = bm + wr + mi * 16 + quad * 4;
          int col = cb + wc + ni * 16 + l16;
          float bv_ = bia[col];
          int bb2 = row >> 11, s = row & 2047, hh = col >> 6, dh = col & 63;
          ushort4 o4;
          o4.x = f2bf(acc[mi][ni][0] + bv_);
          o4.y = f2bf(acc[mi][ni][1] + bv_);
          o4.z = f2bf(acc[mi][ni][2] + bv_);
          o4.w = f2bf(acc[mi][ni][3] + bv_);
          *(ushort4*)(&ov[(((size_t)bb2 * NH + hh) * DH + dh) * SS + s]) = o4;
        }
    } else {
      u16* o = seg == 0 ? oq : ok;
      float sc = seg == 0 ? (0.125f * 1.44269504f) : 1.0f;
#pragma unroll
      for (int mi = 0; mi < 4; ++mi)
#pragma unroll
        for (int ni = 0; ni < 4; ++ni)
#pragma unroll
          for (int r = 0; r < 4; ++r) {
            int row = bm + wr + mi * 16 + quad * 4 + r;
            int col = cb + wc + ni * 16 + l16;
            float v = (acc[mi][ni][r] + bia[col]) * sc;
            int bb2 = row >> 11, s = row & 2047, hh = col >> 6, dh = col & 63;
            o[((((size_t)bb2 * NH + hh) * SS) + s) * DH + dh] = f2bf(v);
          }
    }
  }
}

// ---------------- flash attention (transposed-S, register P, DMA staging) --
// grid: (S/128, NH, BB), block 256 (4 waves, 32 q-rows each)
// R11 (deferred-PV pipeline) vs R0 baseline:
//   THEORY: R3 (kv rotation) and R4 (half the barriers) both changed
//   nothing -> the MFMA/VALU serialization is INTRA-wave: the step's chain
//   QK -> exp(QK) -> PV(exp) leaves the wave no independent VALU work to
//   issue under MFMA execution (MFMA = 1-cyc issue + ~5-cyc pipe shadow).
//   FIX: defer PV by one kv-tile. Step n: per t-quarter {QK(n,t) 4 MFMA} ->
//   {PV(n-1,t) 8 MFMA, independent, covers QK latency} -> {exp(n,t), fills
//   the MFMA pipe shadow}. pb (packed P) carries across steps.
//   Structure: K double-buffered (unchanged lifetime); V in 4 slots since
//   V(m) is now read at step m+1: staged during m-1, read m+1, re-staged
//   during m+3 -> per-step barriers separate read/write on every edge.
//   First-step PV: pb zero-init multiplies PRESTAGED slot-3 V (finite x 0
//   = exact 0; garbage LDS could be Inf/NaN so slot 3 gets V0 too).
//   Per-accumulator summation order is unchanged -> bitwise-identical
//   output to R0.
__global__ __launch_bounds__(256) void k_attn(const u16* __restrict__ Q,
                                              const u16* __restrict__ Kg,
                                              const u16* __restrict__ VT,
                                              u16* __restrict__ ctx) {
  __shared__ __align__(16) u16 Ks[2][64][64];   // 16 KB, K double-buffer
  __shared__ __align__(16) u16 Vts[4][64][64];  // 32 KB, V 4-slot, [d][kv]
  int tid = threadIdx.x;
  int wave = tid >> 6, lane = tid & 63, quad = lane >> 4, l16 = lane & 15;
  int q0 = blockIdx.x * 128;
  int h = blockIdx.y, b = blockIdx.z;
  size_t bh = ((size_t)b * NH + h) * SS * DH;
  const u16* Qp = Q + bh + (size_t)(q0 + wave * 32) * DH;
  const u16* Kp = Kg + bh;
  const u16* Vp = VT + ((size_t)b * NH + h) * DH * SS;  // [Dh][S]

  // Q as B-operand fragments: B[k=d=quad*8+j][n=q=l16], 2 q-tiles
  bf16x8 qf[2][2];
#pragma unroll
  for (int qt = 0; qt < 2; ++qt) {
    qf[qt][0] = ld_bf8(Qp + (qt * 16 + l16) * DH + quad * 8);
    qf[qt][1] = ld_bf8(Qp + (qt * 16 + l16) * DH + 32 + quad * 8);
  }

  f32x4 Ot[4][2] = {};           // [d-tile][q-tile], O^T C-layout
  float lrun[2] = {0.0f, 0.0f};  // per-lane partial sums (q = l16)
  bf16x4 pb[2][4] = {};          // packed P of the PREVIOUS tile (zero: step0)
  const f32x4 fz = {0.0f, 0.0f, 0.0f, 0.0f};

  // ---- staging constants (global side carries the swizzle) ----
  int lrow = lane >> 3;            // 0..7 (row within 8-row DMA chunk)
  int lcb = (lane & 7) ^ lrow;     // swizzled global col-block
  const u16* kdma[2];
  const u16* vdma[2];
  u16* kl[2];
  u16* vl[2];
#pragma unroll
  for (int i = 0; i < 2; ++i) {
    int chunk = wave * 2 + i;      // 0..7, 8 rows each
    kdma[i] = Kp + (size_t)(chunk * 8 + lrow) * DH + lcb * 8;
    vdma[i] = Vp + (size_t)(chunk * 8 + lrow) * SS + lcb * 8;
    kl[i] = &Ks[0][chunk * 8][0];
    vl[i] = &Vts[0][chunk * 8][0];
  }

  // ---- hoisted frag pointers (loop addressing = base + literal) ----
  int e7 = l16 & 7, qh = quad >> 1, qp = quad & 1;
  const u16* kfr0 = &Ks[0][l16][(quad ^ e7) * 8];        // d-blocks 0..3
  const u16* kfr1 = &Ks[0][l16][((quad + 4) ^ e7) * 8];  // d-blocks 4..7
  const u16* vfr[4];
#pragma unroll
  for (int c = 0; c < 4; ++c)
    vfr[c] = &Vts[0][l16][((2 * c + qh) ^ e7) * 8 + qp * 4];

  // ---- prestage: K0 -> kbuf0, V0 -> vslot0 AND vslot3 (slot3 = finite
  //      data for the zero-pb PV of step 0; 0 * finite = exact 0) ----
#pragma unroll
  for (int i = 0; i < 2; ++i) {
    __builtin_amdgcn_global_load_lds(
        (const __attribute__((address_space(1))) void*)kdma[i],
        (__attribute__((address_space(3))) void*)kl[i], 16, 0, 0);
    __builtin_amdgcn_global_load_lds(
        (const __attribute__((address_space(1))) void*)vdma[i],
        (__attribute__((address_space(3))) void*)vl[i], 16, 0, 0);
    __builtin_amdgcn_global_load_lds(
        (const __attribute__((address_space(1))) void*)vdma[i],
        (__attribute__((address_space(3))) void*)(vl[i] + 3 * 4096), 16, 0, 0);
  }
  __syncthreads();

  int kv = 64;  // kv offset of the next tile to stage

  // step n: KP=n&1 (QK K-buf), KD=(n+1)&1 (K stage dst),
  //         VPV=(n+3)&3 (V slot of tile n-1), VD=(n+1)&3 (V stage dst)
#define ATTN_STEP(KP, KD, VPV, VD)                                            \
  {                                                                           \
    if (kv < SS) {                                                            \
      _Pragma("unroll") for (int i = 0; i < 2; ++i) {                         \
        __builtin_amdgcn_global_load_lds(                                     \
            (const __attribute__((address_space(1))) void*)(kdma[i] +         \
                                                            (size_t)kv * DH), \
            (__attribute__((address_space(3))) void*)(kl[i] + (KD) * 4096),   \
            16, 0, 0);                                                        \
        __builtin_amdgcn_global_load_lds(                                     \
            (const __attribute__((address_space(1))) void*)(vdma[i] + kv),    \
            (__attribute__((address_space(3))) void*)(vl[i] + (VD) * 4096),   \
            16, 0, 0);                                                        \
      }                                                                       \
    }                                                                         \
    _Pragma("unroll") for (int t = 0; t < 4; ++t) {                           \
      bf16x8 kb0 = *(const bf16x8*)(kfr0 + (KP) * 4096 + t * 1024);           \
      bf16x8 kb1 = *(const bf16x8*)(kfr1 + (KP) * 4096 + t * 1024);           \
      f32x4 z0 = MFMA16(kb0, qf[0][0], fz);                                   \
      z0 = MFMA16(kb1, qf[0][1], z0);                                         \
      f32x4 z1 = MFMA16(kb0, qf[1][0], fz);                                   \
      z1 = MFMA16(kb1, qf[1][1], z1);                                         \
      bf16x4 po0 = pb[0][t], po1 = pb[1][t];                                  \
      _Pragma("unroll") for (int dt = 0; dt < 4; ++dt) {                      \
        bf16x4 va = *(const bf16x4*)(vfr[t] + (VPV) * 4096 + dt * 1024);      \
        Ot[dt][0] = MFMA16K16(va, po0, Ot[dt][0]);                            \
        Ot[dt][1] = MFMA16K16(va, po1, Ot[dt][1]);                            \
      }                                                                       \
      unsigned u0 = __builtin_bit_cast(unsigned,                              \
                                       __builtin_amdgcn_exp2f(z0[0]));        \
      unsigned u1 = __builtin_bit_cast(unsigned,                              \
                                       __builtin_amdgcn_exp2f(z0[1]));        \
      unsigned u2 = __builtin_bit_cast(unsigned,                              \
                                       __builtin_amdgcn_exp2f(z0[2]));        \
      unsigned u3 = __builtin_bit_cast(unsigned,                              \
                                       __builtin_amdgcn_exp2f(z0[3]));        \
      unsigned w0 = __builtin_amdgcn_perm(u1, u0, 0x07060302u);               \
      unsigned w1 = __builtin_amdgcn_perm(u3, u2, 0x07060302u);               \
      lrun[0] += __builtin_bit_cast(float, w0 << 16) +                        \
                 __builtin_bit_cast(float, w0 & 0xffff0000u) +                \
                 __builtin_bit_cast(float, w1 << 16) +                        \
                 __builtin_bit_cast(float, w1 & 0xffff0000u);                 \
      uintx2 wv0;                                                             \
      wv0[0] = w0;                                                            \
      wv0[1] = w1;                                                            \
      pb[0][t] = __builtin_bit_cast(bf16x4, wv0);                             \
      unsigned v0 = __builtin_bit_cast(unsigned,                              \
                                       __builtin_amdgcn_exp2f(z1[0]));        \
      unsigned v1 = __builtin_bit_cast(unsigned,                              \
                                       __builtin_amdgcn_exp2f(z1[1]));        \
      unsigned v2 = __builtin_bit_cast(unsigned,                              \
                                       __builtin_amdgcn_exp2f(z1[2]));        \
      unsigned v3 = __builtin_bit_cast(unsigned,                              \
                                       __builtin_amdgcn_exp2f(z1[3]));        \
      unsigned x0 = __builtin_amdgcn_perm(v1, v0, 0x07060302u);               \
      unsigned x1 = __builtin_amdgcn_perm(v3, v2, 0x07060302u);               \
      lrun[1] += __builtin_bit_cast(float, x0 << 16) +                        \
                 __builtin_bit_cast(float, x0 & 0xffff0000u) +                \
                 __builtin_bit_cast(float, x1 << 16) +                        \
                 __builtin_bit_cast(float, x1 & 0xffff0000u);                 \
      uintx2 wv1;                                                             \
      wv1[0] = x0;                                                            \
      wv1[1] = x1;                                                            \
      pb[1][t] = __builtin_bit_cast(bf16x4, wv1);                             \
    }                                                                         \
    __syncthreads();                                                          \
    kv += 64;                                                                 \
  }

  for (int n4 = 0; n4 < 8; ++n4) {
    ATTN_STEP(0, 1, 3, 1);
    ATTN_STEP(1, 0, 0, 2);
    ATTN_STEP(0, 1, 1, 3);
    ATTN_STEP(1, 0, 2, 0);
  }
#undef ATTN_STEP

  // epilogue: PV of the last tile (31), V in slot 3 (staged during step 30)
#pragma unroll
  for (int t = 0; t < 4; ++t) {
    bf16x4 po0 = pb[0][t], po1 = pb[1][t];
#pragma unroll
    for (int dt = 0; dt < 4; ++dt) {
      bf16x4 va = *(const bf16x4*)(vfr[t] + 3 * 4096 + dt * 1024);
      Ot[dt][0] = MFMA16K16(va, po0, Ot[dt][0]);
      Ot[dt][1] = MFMA16K16(va, po1, Ot[dt][1]);
    }
  }

  // final normalizer: lanes {l16, +16, +32, +48} hold q=l16 partials
  float inv[2];
#pragma unroll
  for (int qt = 0; qt < 2; ++qt) {
    float l = lrun[qt];
    l += __shfl_xor(l, 16);
    l += __shfl_xor(l, 32);
    inv[qt] = 1.0f / l;
  }

  // write O^T: per lane q = l16 (fixed), d = dt*16 + quad*4 + r (contiguous)
#pragma unroll
  for (int qt = 0; qt < 2; ++qt) {
    int q = q0 + wave * 32 + qt * 16 + l16;
    size_t ob = ((size_t)b * SS + q) * DM + h * DH;
#pragma unroll
    for (int dt = 0; dt < 4; ++dt) {
      uintx2 o;
      o[0] = pack2bf(Ot[dt][qt][0] * inv[qt], Ot[dt][qt][1] * inv[qt]);
      o[1] = pack2bf(Ot[dt][qt][2] * inv[qt], Ot[dt][qt][3] * inv[qt]);
      *(uintx2*)(&ctx[ob + dt * 16 + quad * 4]) = o;
    }
  }
}

extern "C" void kernel_launch(void* const* d_in, const int* in_sizes, int n_in,
                              void* d_out, int out_size, void* d_ws, size_t ws_size,
                              hipStream_t stream) {
  const float* x  = (const float*)d_in[0];
  const float* Wq = (const float*)d_in[1];
  const float* bq = (const float*)d_in[2];
  const float* Wk = (const float*)d_in[3];
  const float* bk = (const float*)d_in[4];
  const float* Wv = (const float*)d_in[5];
  const float* bv = (const float*)d_in[6];
  const float* Wo = (const float*)d_in[7];
  const float* bo = (const float*)d_in[8];
  float* out = (float*)d_out;

  char* ws = (char*)d_ws;
  u16* xb = (u16*)(ws);                        // 16 MB  [8192,1024] bf16
  u16* Wt = (u16*)(ws + (16u << 20));          //  8 MB  [4096,1024] bf16
  u16* Qb = (u16*)(ws + (24u << 20));          // 16 MB  [B,H,S,Dh] (pre-scaled)
  u16* Kb = (u16*)(ws + (40u << 20));          // 16 MB  [B,H,S,Dh]
  u16* VT = (u16*)(ws + (56u << 20));          // 16 MB  [B,H,Dh,S]
  u16* Cb = (u16*)(ws + (72u << 20));          // 16 MB  [B,S,D] bf16 ctx

  k_cvt_x<<<MROWS * DM / 1024, 256, 0, stream>>>(x, xb);
  k_tw<<<dim3(32, 128), dim3(32, 32), 0, stream>>>(Wq, Wk, Wv, Wo, Wt);
  k_gemm<<<dim3(MROWS / 128, 24), 256, 0, stream>>>(
      xb, Wt, MROWS, 3 * DM, DM, bq, bk, bv, Qb, Kb, VT, nullptr, 1);
  k_attn<<<dim3(SS / 128, NH, BB), 256, 0, stream>>>(Qb, Kb, VT, Cb);
  k_gemm<<<dim3(MROWS / 128, 8), 256, 0, stream>>>(
      Cb, Wt + (size_t)3 * DM * DM, MROWS, DM, DM, bo, nullptr, nullptr,
      nullptr, nullptr, nullptr, out, 0);
}

// Round 6
// 297.798 us; speedup vs baseline: 1.0939x; 1.0939x over previous
//
#include <hip/hip_runtime.h>
#include <hip/hip_bf16.h>

#define DM 1024
#define NH 16
#define DH 64
#define BB 4
#define SS 2048
#define MROWS (BB*SS)   // 8192

typedef unsigned short u16;
typedef short bf16x8 __attribute__((ext_vector_type(8)));
typedef short bf16x4 __attribute__((ext_vector_type(4)));
typedef float f32x4 __attribute__((ext_vector_type(4)));
typedef unsigned uintx2 __attribute__((ext_vector_type(2)));

#define MFMA16(a, b, c) __builtin_amdgcn_mfma_f32_16x16x32_bf16((a), (b), (c), 0, 0, 0)
#define MFMA16K16(a, b, c) __builtin_amdgcn_mfma_f32_16x16x16bf16_1k((a), (b), (c), 0, 0, 0)

__device__ __forceinline__ u16 f2bf(float f) {
  union { float f; unsigned u; } v; v.f = f;
  unsigned u = v.u;
  return (u16)((u + 0x7fffu + ((u >> 16) & 1u)) >> 16);
}

// pack two floats -> u32 of two RNE bf16 (lo = a, hi = b)
__device__ __forceinline__ unsigned pack2bf(float a, float b) {
  __hip_bfloat162 h = __float22bfloat162_rn(make_float2(a, b));
  unsigned u;
  __builtin_memcpy(&u, &h, 4);
  return u;
}

__device__ __forceinline__ bf16x8 ld_bf8(const u16* p) {
  return *(const bf16x8*)p;
}

// ---------------- convert x (fp32 -> bf16), 4 elems/thread ----------------
__global__ __launch_bounds__(256) void k_cvt_x(const float* __restrict__ x,
                                               u16* __restrict__ xb) {
  int i = (blockIdx.x * 256 + threadIdx.x) * 4;
  float4 v = *(const float4*)(x + i);
  ushort4 o;
  o.x = f2bf(v.x); o.y = f2bf(v.y); o.z = f2bf(v.z); o.w = f2bf(v.w);
  *(ushort4*)(xb + i) = o;
}

// ------------- transpose weights W[K,N] -> Wt[N,K] bf16, 4 segments -------
__global__ __launch_bounds__(1024) void k_tw(const float* __restrict__ Wq,
                                             const float* __restrict__ Wk,
                                             const float* __restrict__ Wv,
                                             const float* __restrict__ Wo,
                                             u16* __restrict__ Wt) {
  __shared__ float t[32][33];
  int k0 = blockIdx.x * 32;
  int seg = blockIdx.y >> 5;
  int n0 = (blockIdx.y & 31) * 32;
  const float* W = seg == 0 ? Wq : seg == 1 ? Wk : seg == 2 ? Wv : Wo;
  int tx = threadIdx.x, ty = threadIdx.y;
  t[ty][tx] = W[(size_t)(k0 + ty) * DM + n0 + tx];
  __syncthreads();
  Wt[(size_t)(seg * DM + n0 + ty) * DM + k0 + tx] = f2bf(t[tx][ty]);
}

// ---------------- GEMM (128-tile, out-proj only): C = A * Bt^T + bias -----
__global__ __launch_bounds__(256) void k_gemm(
    const u16* __restrict__ A, const u16* __restrict__ Bt,
    int M, int N, int K,
    const float* __restrict__ b0,
    float* __restrict__ of) {
  __shared__ __align__(16) u16 As[128 * 32];
  __shared__ __align__(16) u16 Bs[128 * 32];
  int tid = threadIdx.x;
  int wave = tid >> 6, lane = tid & 63, quad = lane >> 4, l16 = lane & 15;
  int bm = blockIdx.x * 128, bn = blockIdx.y * 128;
  int wr = (wave >> 1) * 64, wc = (wave & 1) * 64;
  f32x4 acc[4][4] = {};

  const u16* ga = A + (size_t)(bm + wave * 32 + (lane >> 2)) * K + (lane & 3) * 8;
  const u16* gb = Bt + (size_t)(bn + wave * 32 + (lane >> 2)) * K + (lane & 3) * 8;
  u16* lda = &As[wave * 1024];
  u16* ldb = &Bs[wave * 1024];

  for (int k0 = 0; k0 < K; k0 += 32) {
#pragma unroll
    for (int i = 0; i < 2; ++i) {
      __builtin_amdgcn_global_load_lds(
          (const __attribute__((address_space(1))) void*)(ga + (size_t)i * 16 * K + k0),
          (__attribute__((address_space(3))) void*)(lda + i * 512), 16, 0, 0);
      __builtin_amdgcn_global_load_lds(
          (const __attribute__((address_space(1))) void*)(gb + (size_t)i * 16 * K + k0),
          (__attribute__((address_space(3))) void*)(ldb + i * 512), 16, 0, 0);
    }
    __syncthreads();
    bf16x8 af[4], bfr[4];
#pragma unroll
    for (int mi = 0; mi < 4; ++mi)
      af[mi] = *(const bf16x8*)(&As[(wr + mi * 16 + l16) * 32 + quad * 8]);
#pragma unroll
    for (int ni = 0; ni < 4; ++ni)
      bfr[ni] = *(const bf16x8*)(&Bs[(wc + ni * 16 + l16) * 32 + quad * 8]);
#pragma unroll
    for (int mi = 0; mi < 4; ++mi)
#pragma unroll
      for (int ni = 0; ni < 4; ++ni)
        acc[mi][ni] = MFMA16(af[mi], bfr[ni], acc[mi][ni]);
    __syncthreads();
  }

#pragma unroll
  for (int mi = 0; mi < 4; ++mi)
#pragma unroll
    for (int ni = 0; ni < 4; ++ni)
#pragma unroll
      for (int r = 0; r < 4; ++r) {
        int row = bm + wr + mi * 16 + quad * 4 + r;
        int col = bn + wc + ni * 16 + l16;
        of[(size_t)row * N + col] = acc[mi][ni][r] + b0[col];
      }
}

// ---------------- QKV GEMM: 256x256 tile, BK=64, 8 waves, swizzled LDS ----
// C[8192,3072] = A[8192,1024] * Bt[3072,1024]^T + bias, fused QKV scatter.
// Design (R12):
//  - per-wave output 128x64 (wr=wave>>2, wc=wave&3): MFMA:ds_read = 64:24
//    per K-tile (vs 16:8 at 128^2/BK=32) -> LDS-read no longer the binding
//    pipe (per-CU: 512 MFMA ~2480cyc vs 192 b128 ~2300cyc).
//  - LDS [2][256][64] bf16 for A and B (128 KB, double-buffered, 1 blk/CU).
//  - XOR swizzle (k_attn-proven): within each 128B row, 16B-block b holds
//    logical block b^(row&7). BK=64 rows are 128B -> unswizzled reads would
//    be 16 addr/bank (2x the b128 floor of 8); swizzled = floor.
//    Staging writes linearly (global_load_lds lane*16), source address
//    carries the swizzle: lane l covers row w*8+(l>>3)+j*64, phys block
//    l&7 = logical block (l&7)^(l>>3)  [row&7 == l>>3].
//    Read: frag(row, s, quad) at phys block (s*4+quad)^(row&7), row&7=l16&7.
//  - issue-early staging: ALL 8 gload_lds for tile t+1 (-> buf c^1) at the
//    top of group t; the group's ~2400 cyc of compute covers the latency, so
//    the barrier's vmcnt(0) drain is cheap. ONE barrier per K-tile.
//    Hazards: stages target the non-read buffer; __syncthreads (compiler
//    emits vmcnt(0)+lgkmcnt(0) before s_barrier) fences reads/writes both
//    ways at the group boundary.
//  - K-summation order identical to the old kernel -> bitwise-same outputs.
__global__ __launch_bounds__(512, 2) void k_gemm3(
    const u16* __restrict__ A, const u16* __restrict__ Bt,
    const float* __restrict__ b0, const float* __restrict__ b1,
    const float* __restrict__ b2,
    u16* __restrict__ oq, u16* __restrict__ ok, u16* __restrict__ ov) {
  __shared__ __align__(16) u16 As[2][256][64];  // 64 KB
  __shared__ __align__(16) u16 Bs[2][256][64];  // 64 KB
  const int K = DM;
  int tid = threadIdx.x;
  int wave = tid >> 6, lane = tid & 63, quad = lane >> 4, l16 = lane & 15;
  int wr = wave >> 2, wc = wave & 3;
  int bm = blockIdx.x * 256, bn = blockIdx.y * 256;

  f32x4 acc[8][4] = {};

  // ---- staging: per thread 4x16B per operand per tile ----
  int srow = wave * 8 + (lane >> 3);               // 0..63 (+ j*64)
  int scol = ((lane & 7) ^ (lane >> 3)) * 8;       // swizzled source col
  const u16* ga = A + (size_t)(bm + srow) * K + scol;
  const u16* gb = Bt + (size_t)(bn + srow) * K + scol;
  u16* aw[2] = {&As[0][wave * 8][0], &As[1][wave * 8][0]};
  u16* bw[2] = {&Bs[0][wave * 8][0], &Bs[1][wave * 8][0]};

  // ---- read-side frag base pointers [buf][s] ----
  int e7 = l16 & 7;
  const u16* aP[2][2];
  const u16* bP[2][2];
#pragma unroll
  for (int s = 0; s < 2; ++s) {
    int blk = ((s * 4 + quad) ^ e7) * 8;
    aP[0][s] = &As[0][wr * 128 + l16][0] + blk;
    aP[1][s] = &As[1][wr * 128 + l16][0] + blk;
    bP[0][s] = &Bs[0][wc * 64 + l16][0] + blk;
    bP[1][s] = &Bs[1][wc * 64 + l16][0] + blk;
  }

#define STAGE3(T, BUF)                                                        \
  {                                                                           \
    _Pragma("unroll") for (int j = 0; j < 4; ++j) {                           \
      __builtin_amdgcn_global_load_lds(                                       \
          (const __attribute__((address_space(1))) void*)(                    \
              ga + (size_t)(j * 64) * K + (T) * 64),                          \
          (__attribute__((address_space(3))) void*)(aw[BUF] + j * 4096),      \
          16, 0, 0);                                                          \
      __builtin_amdgcn_global_load_lds(                                       \
          (const __attribute__((address_space(1))) void*)(                    \
              gb + (size_t)(j * 64) * K + (T) * 64),                          \
          (__attribute__((address_space(3))) void*)(bw[BUF] + j * 4096),      \
          16, 0, 0);                                                          \
    }                                                                         \
  }

#define COMPUTE3(BUF)                                                        \
  {                                                                           \
    bf16x8 bfr[4][2];                                                         \
    _Pragma("unroll") for (int n = 0; n < 4; ++n)                             \
        _Pragma("unroll") for (int s = 0; s < 2; ++s)                         \
            bfr[n][s] = *(const bf16x8*)(bP[BUF][s] + n * 1024);              \
    _Pragma("unroll") for (int q = 0; q < 4; ++q) {                           \
      bf16x8 af[2][2];                                                        \
      _Pragma("unroll") for (int mm = 0; mm < 2; ++mm)                        \
          _Pragma("unroll") for (int s = 0; s < 2; ++s)                       \
              af[mm][s] =                                                     \
                  *(const bf16x8*)(aP[BUF][s] + (q * 2 + mm) * 1024);         \
      __builtin_amdgcn_s_setprio(1);                                          \
      _Pragma("unroll") for (int mm = 0; mm < 2; ++mm)                        \
          _Pragma("unroll") for (int n = 0; n < 4; ++n) {                     \
        acc[q * 2 + mm][n] =                                                  \
            MFMA16(af[mm][0], bfr[n][0], acc[q * 2 + mm][n]);                 \
        acc[q * 2 + mm][n] =                                                  \
            MFMA16(af[mm][1], bfr[n][1], acc[q * 2 + mm][n]);                 \
      }                                                                       \
      __builtin_amdgcn_s_setprio(0);                                          \
    }                                                                         \
  }

  STAGE3(0, 0);
  __syncthreads();
#pragma unroll 1
  for (int tt = 0; tt < 8; ++tt) {
    STAGE3(tt * 2 + 1, 1);
    COMPUTE3(0);
    __syncthreads();
    if (tt < 7) STAGE3(tt * 2 + 2, 0);
    COMPUTE3(1);
    __syncthreads();
  }
#undef STAGE3
#undef COMPUTE3

  // ---- epilogue: bias + QKV scatter (BN=256 divides the 1024 segments) ---
  int seg = bn >> 10;
  const float* bia = seg == 0 ? b0 : seg == 1 ? b1 : b2;
  int cb = bn & 1023;
  if (seg == 2) {
#pragma unroll
    for (int m = 0; m < 8; ++m)
#pragma unroll
      for (int n = 0; n < 4; ++n) {
        int row = bm + wr * 128 + m * 16 + quad * 4;
        int col = cb + wc * 64 + n * 16 + l16;
        float bv_ = bia[col];
        int bb2 = row >> 11, s = row & 2047, hh = col >> 6, dh = col & 63;
        ushort4 o4;
        o4.x = f2bf(acc[m][n][0] + bv_);
        o4.y = f2bf(acc[m][n][1] + bv_);
        o4.z = f2bf(acc[m][n][2] + bv_);
        o4.w = f2bf(acc[m][n][3] + bv_);
        *(ushort4*)(&ov[(((size_t)bb2 * NH + hh) * DH + dh) * SS + s]) = o4;
      }
  } else {
    u16* o = seg == 0 ? oq : ok;
    float sc = seg == 0 ? (0.125f * 1.44269504f) : 1.0f;
#pragma unroll
    for (int m = 0; m < 8; ++m)
#pragma unroll
      for (int n = 0; n < 4; ++n)
#pragma unroll
        for (int r = 0; r < 4; ++r) {
          int row = bm + wr * 128 + m * 16 + quad * 4 + r;
          int col = cb + wc * 64 + n * 16 + l16;
          float v = (acc[m][n][r] + bia[col]) * sc;
          int bb2 = row >> 11, s = row & 2047, hh = col >> 6, dh = col & 63;
          o[((((size_t)bb2 * NH + hh) * SS) + s) * DH + dh] = f2bf(v);
        }
  }
}

// ---------------- flash attention (R0-exact: the 105us best) --------------
// grid: (S/128, NH, BB), block 256 (4 waves, 32 q-rows each)
__global__ __launch_bounds__(256) void k_attn(const u16* __restrict__ Q,
                                              const u16* __restrict__ Kg,
                                              const u16* __restrict__ VT,
                                              u16* __restrict__ ctx) {
  __shared__ __align__(16) u16 Ks[2][64][64];
  __shared__ __align__(16) u16 Vts[2][64][64];  // [d][kv], swizzled
  int tid = threadIdx.x;
  int wave = tid >> 6, lane = tid & 63, quad = lane >> 4, l16 = lane & 15;
  int q0 = blockIdx.x * 128;
  int h = blockIdx.y, b = blockIdx.z;
  size_t bh = ((size_t)b * NH + h) * SS * DH;
  const u16* Qp = Q + bh + (size_t)(q0 + wave * 32) * DH;
  const u16* Kp = Kg + bh;
  const u16* Vp = VT + ((size_t)b * NH + h) * DH * SS;  // [Dh][S]

  // Q as B-operand fragments: B[k=d=quad*8+j][n=q=l16], 2 q-tiles
  bf16x8 qf[2][2];
#pragma unroll
  for (int qt = 0; qt < 2; ++qt) {
    qf[qt][0] = ld_bf8(Qp + (qt * 16 + l16) * DH + quad * 8);
    qf[qt][1] = ld_bf8(Qp + (qt * 16 + l16) * DH + 32 + quad * 8);
  }

  f32x4 Ot[4][2] = {};           // [d-tile][q-tile], O^T C-layout
  float lrun[2] = {0.0f, 0.0f};  // per-lane partial sums (q = l16)

  // ---- staging constants (global side carries the swizzle) ----
  int lrow = lane >> 3;            // 0..7 (row within 8-row DMA chunk)
  int lcb = (lane & 7) ^ lrow;     // swizzled global col-block
  const u16* kdma[2];
  const u16* vdma[2];
  u16* kl[2];
  u16* vl[2];
#pragma unroll
  for (int i = 0; i < 2; ++i) {
    int chunk = wave * 2 + i;      // 0..7, 8 rows each
    kdma[i] = Kp + (size_t)(chunk * 8 + lrow) * DH + lcb * 8;
    vdma[i] = Vp + (size_t)(chunk * 8 + lrow) * SS + lcb * 8;
    kl[i] = &Ks[0][chunk * 8][0];
    vl[i] = &Vts[0][chunk * 8][0];
  }

  // ---- hoisted frag pointers (loop addressing = base + literal) ----
  int e7 = l16 & 7, qh = quad >> 1, qp = quad & 1;
  const u16* kfr0 = &Ks[0][l16][(quad ^ e7) * 8];        // d-blocks 0..3
  const u16* kfr1 = &Ks[0][l16][((quad + 4) ^ e7) * 8];  // d-blocks 4..7
  const u16* vfr[4];
#pragma unroll
  for (int c = 0; c < 4; ++c)
    vfr[c] = &Vts[0][l16][((2 * c + qh) ^ e7) * 8 + qp * 4];

  // ---- prestage tile kv=0 into buffer 0 ----
#pragma unroll
  for (int i = 0; i < 2; ++i) {
    __builtin_amdgcn_global_load_lds(
        (const __attribute__((address_space(1))) void*)kdma[i],
        (__attribute__((address_space(3))) void*)kl[i], 16, 0, 0);
    __builtin_amdgcn_global_load_lds(
        (const __attribute__((address_space(1))) void*)vdma[i],
        (__attribute__((address_space(3))) void*)vl[i], 16, 0, 0);
  }
  __syncthreads();

  int kv = 64;  // next tile to stage

#define ATTN_STEP(P)                                                          \
  {                                                                           \
    f32x4 s[2][4];                                                            \
    _Pragma("unroll") for (int t = 0; t < 4; ++t) {                           \
      bf16x8 kb0 = *(const bf16x8*)(kfr0 + (P) * 4096 + t * 1024);            \
      bf16x8 kb1 = *(const bf16x8*)(kfr1 + (P) * 4096 + t * 1024);            \
      _Pragma("unroll") for (int qt = 0; qt < 2; ++qt) {                      \
        f32x4 z = {};                                                         \
        z = MFMA16(kb0, qf[qt][0], z);                                        \
        z = MFMA16(kb1, qf[qt][1], z);                                        \
        s[qt][t] = z;                                                         \
      }                                                                       \
    }                                                                         \
    if (kv < SS) {                                                            \
      _Pragma("unroll") for (int i = 0; i < 2; ++i) {                         \
        __builtin_amdgcn_global_load_lds(                                     \
            (const __attribute__((address_space(1))) void*)(kdma[i] +         \
                                                            (size_t)kv * DH), \
            (__attribute__((address_space(3))) void*)(kl[i] +                 \
                                                      (1 - (P)) * 4096),      \
            16, 0, 0);                                                        \
        __builtin_amdgcn_global_load_lds(                                     \
            (const __attribute__((address_space(1))) void*)(vdma[i] + kv),    \
            (__attribute__((address_space(3))) void*)(vl[i] +                 \
                                                      (1 - (P)) * 4096),      \
            16, 0, 0);                                                        \
      }                                                                       \
    }                                                                         \
    bf16x4 pb[2][4];                                                          \
    _Pragma("unroll") for (int qt = 0; qt < 2; ++qt)                          \
        _Pragma("unroll") for (int t = 0; t < 4; ++t) {                       \
      unsigned u0 = __builtin_bit_cast(                                       \
          unsigned, __builtin_amdgcn_exp2f(s[qt][t][0]));                     \
      unsigned u1 = __builtin_bit_cast(                                       \
          unsigned, __builtin_amdgcn_exp2f(s[qt][t][1]));                     \
      unsigned u2 = __builtin_bit_cast(                                       \
          unsigned, __builtin_amdgcn_exp2f(s[qt][t][2]));                     \
      unsigned u3 = __builtin_bit_cast(                                       \
          unsigned, __builtin_amdgcn_exp2f(s[qt][t][3]));                     \
      unsigned w0 = __builtin_amdgcn_perm(u1, u0, 0x07060302u);               \
      unsigned w1 = __builtin_amdgcn_perm(u3, u2, 0x07060302u);               \
      lrun[qt] += __builtin_bit_cast(float, w0 << 16) +                       \
                  __builtin_bit_cast(float, w0 & 0xffff0000u) +               \
                  __builtin_bit_cast(float, w1 << 16) +                       \
                  __builtin_bit_cast(float, w1 & 0xffff0000u);                \
      uintx2 w;                                                               \
      w[0] = w0;                                                              \
      w[1] = w1;                                                              \
      pb[qt][t] = __builtin_bit_cast(bf16x4, w);                              \
    }                                                                         \
    _Pragma("unroll") for (int c = 0; c < 4; ++c)                             \
        _Pragma("unroll") for (int dt = 0; dt < 4; ++dt) {                    \
      bf16x4 va = *(const bf16x4*)(vfr[c] + (P) * 4096 + dt * 1024);          \
      _Pragma("unroll") for (int qt = 0; qt < 2; ++qt)                        \
          Ot[dt][qt] = MFMA16K16(va, pb[qt][c], Ot[dt][qt]);                  \
    }                                                                         \
    __syncthreads();                                                          \
    kv += 64;                                                                 \
  }

  for (int it = 0; it < SS / 128; ++it) {
    ATTN_STEP(0);
    ATTN_STEP(1);
  }
#undef ATTN_STEP

  // final normalizer: lanes {l16, +16, +32, +48} hold q=l16 partials
  float inv[2];
#pragma unroll
  for (int qt = 0; qt < 2; ++qt) {
    float l = lrun[qt];
    l += __shfl_xor(l, 16);
    l += __shfl_xor(l, 32);
    inv[qt] = 1.0f / l;
  }

  // write O^T: per lane q = l16 (fixed), d = dt*16 + quad*4 + r (contiguous)
#pragma unroll
  for (int qt = 0; qt < 2; ++qt) {
    int q = q0 + wave * 32 + qt * 16 + l16;
    size_t ob = ((size_t)b * SS + q) * DM + h * DH;
#pragma unroll
    for (int dt = 0; dt < 4; ++dt) {
      uintx2 o;
      o[0] = pack2bf(Ot[dt][qt][0] * inv[qt], Ot[dt][qt][1] * inv[qt]);
      o[1] = pack2bf(Ot[dt][qt][2] * inv[qt], Ot[dt][qt][3] * inv[qt]);
      *(uintx2*)(&ctx[ob + dt * 16 + quad * 4]) = o;
    }
  }
}

extern "C" void kernel_launch(void* const* d_in, const int* in_sizes, int n_in,
                              void* d_out, int out_size, void* d_ws, size_t ws_size,
                              hipStream_t stream) {
  const float* x  = (const float*)d_in[0];
  const float* Wq = (const float*)d_in[1];
  const float* bq = (const float*)d_in[2];
  const float* Wk = (const float*)d_in[3];
  const float* bk = (const float*)d_in[4];
  const float* Wv = (const float*)d_in[5];
  const float* bv = (const float*)d_in[6];
  const float* Wo = (const float*)d_in[7];
  const float* bo = (const float*)d_in[8];
  float* out = (float*)d_out;

  char* ws = (char*)d_ws;
  u16* xb = (u16*)(ws);                        // 16 MB  [8192,1024] bf16
  u16* Wt = (u16*)(ws + (16u << 20));          //  8 MB  [4096,1024] bf16
  u16* Qb = (u16*)(ws + (24u << 20));          // 16 MB  [B,H,S,Dh] (pre-scaled)
  u16* Kb = (u16*)(ws + (40u << 20));          // 16 MB  [B,H,S,Dh]
  u16* VT = (u16*)(ws + (56u << 20));          // 16 MB  [B,H,Dh,S]
  u16* Cb = (u16*)(ws + (72u << 20));          // 16 MB  [B,S,D] bf16 ctx

  k_cvt_x<<<MROWS * DM / 1024, 256, 0, stream>>>(x, xb);
  k_tw<<<dim3(32, 128), dim3(32, 32), 0, stream>>>(Wq, Wk, Wv, Wo, Wt);
  k_gemm3<<<dim3(MROWS / 256, 12), 512, 0, stream>>>(
      xb, Wt, bq, bk, bv, Qb, Kb, VT);
  k_attn<<<dim3(SS / 128, NH, BB), 256, 0, stream>>>(Qb, Kb, VT, Cb);
  k_gemm<<<dim3(MROWS / 128, 8), 256, 0, stream>>>(
      Cb, Wt + (size_t)3 * DM * DM, MROWS, DM, DM, bo, out);
}

// Round 7
// 296.535 us; speedup vs baseline: 1.0986x; 1.0043x over previous
//
#include <hip/hip_runtime.h>
#include <hip/hip_bf16.h>

#define DM 1024
#define NH 16
#define DH 64
#define BB 4
#define SS 2048
#define MROWS (BB*SS)   // 8192

typedef unsigned short u16;
typedef short bf16x8 __attribute__((ext_vector_type(8)));
typedef short bf16x4 __attribute__((ext_vector_type(4)));
typedef float f32x4 __attribute__((ext_vector_type(4)));
typedef unsigned uintx2 __attribute__((ext_vector_type(2)));

#define MFMA16(a, b, c) __builtin_amdgcn_mfma_f32_16x16x32_bf16((a), (b), (c), 0, 0, 0)
#define MFMA16K16(a, b, c) __builtin_amdgcn_mfma_f32_16x16x16bf16_1k((a), (b), (c), 0, 0, 0)

__device__ __forceinline__ u16 f2bf(float f) {
  union { float f; unsigned u; } v; v.f = f;
  unsigned u = v.u;
  return (u16)((u + 0x7fffu + ((u >> 16) & 1u)) >> 16);
}

// pack two floats -> u32 of two RNE bf16 (lo = a, hi = b)
__device__ __forceinline__ unsigned pack2bf(float a, float b) {
  __hip_bfloat162 h = __float22bfloat162_rn(make_float2(a, b));
  unsigned u;
  __builtin_memcpy(&u, &h, 4);
  return u;
}

__device__ __forceinline__ bf16x8 ld_bf8(const u16* p) {
  return *(const bf16x8*)p;
}

// ---------------- convert x (fp32 -> bf16), 4 elems/thread ----------------
__global__ __launch_bounds__(256) void k_cvt_x(const float* __restrict__ x,
                                               u16* __restrict__ xb) {
  int i = (blockIdx.x * 256 + threadIdx.x) * 4;
  float4 v = *(const float4*)(x + i);
  ushort4 o;
  o.x = f2bf(v.x); o.y = f2bf(v.y); o.z = f2bf(v.z); o.w = f2bf(v.w);
  *(ushort4*)(xb + i) = o;
}

// ------------- transpose weights W[K,N] -> Wt[N,K] bf16, 4 segments -------
__global__ __launch_bounds__(1024) void k_tw(const float* __restrict__ Wq,
                                             const float* __restrict__ Wk,
                                             const float* __restrict__ Wv,
                                             const float* __restrict__ Wo,
                                             u16* __restrict__ Wt) {
  __shared__ float t[32][33];
  int k0 = blockIdx.x * 32;
  int seg = blockIdx.y >> 5;
  int n0 = (blockIdx.y & 31) * 32;
  const float* W = seg == 0 ? Wq : seg == 1 ? Wk : seg == 2 ? Wv : Wo;
  int tx = threadIdx.x, ty = threadIdx.y;
  t[ty][tx] = W[(size_t)(k0 + ty) * DM + n0 + tx];
  __syncthreads();
  Wt[(size_t)(seg * DM + n0 + ty) * DM + k0 + tx] = f2bf(t[tx][ty]);
}

// ---------------- GEMM (128-tile, out-proj only): C = A * Bt^T + bias -----
__global__ __launch_bounds__(256) void k_gemm(
    const u16* __restrict__ A, const u16* __restrict__ Bt,
    int M, int N, int K,
    const float* __restrict__ b0,
    float* __restrict__ of) {
  __shared__ __align__(16) u16 As[128 * 32];
  __shared__ __align__(16) u16 Bs[128 * 32];
  int tid = threadIdx.x;
  int wave = tid >> 6, lane = tid & 63, quad = lane >> 4, l16 = lane & 15;
  int bm = blockIdx.x * 128, bn = blockIdx.y * 128;
  int wr = (wave >> 1) * 64, wc = (wave & 1) * 64;
  f32x4 acc[4][4] = {};

  const u16* ga = A + (size_t)(bm + wave * 32 + (lane >> 2)) * K + (lane & 3) * 8;
  const u16* gb = Bt + (size_t)(bn + wave * 32 + (lane >> 2)) * K + (lane & 3) * 8;
  u16* lda = &As[wave * 1024];
  u16* ldb = &Bs[wave * 1024];

  for (int k0 = 0; k0 < K; k0 += 32) {
#pragma unroll
    for (int i = 0; i < 2; ++i) {
      __builtin_amdgcn_global_load_lds(
          (const __attribute__((address_space(1))) void*)(ga + (size_t)i * 16 * K + k0),
          (__attribute__((address_space(3))) void*)(lda + i * 512), 16, 0, 0);
      __builtin_amdgcn_global_load_lds(
          (const __attribute__((address_space(1))) void*)(gb + (size_t)i * 16 * K + k0),
          (__attribute__((address_space(3))) void*)(ldb + i * 512), 16, 0, 0);
    }
    __syncthreads();
    bf16x8 af[4], bfr[4];
#pragma unroll
    for (int mi = 0; mi < 4; ++mi)
      af[mi] = *(const bf16x8*)(&As[(wr + mi * 16 + l16) * 32 + quad * 8]);
#pragma unroll
    for (int ni = 0; ni < 4; ++ni)
      bfr[ni] = *(const bf16x8*)(&Bs[(wc + ni * 16 + l16) * 32 + quad * 8]);
#pragma unroll
    for (int mi = 0; mi < 4; ++mi)
#pragma unroll
      for (int ni = 0; ni < 4; ++ni)
        acc[mi][ni] = MFMA16(af[mi], bfr[ni], acc[mi][ni]);
    __syncthreads();
  }

#pragma unroll
  for (int mi = 0; mi < 4; ++mi)
#pragma unroll
    for (int ni = 0; ni < 4; ++ni)
#pragma unroll
      for (int r = 0; r < 4; ++r) {
        int row = bm + wr + mi * 16 + quad * 4 + r;
        int col = bn + wc + ni * 16 + l16;
        of[(size_t)row * N + col] = acc[mi][ni][r] + b0[col];
      }
}

// ---------------- QKV GEMM: 256x256, BK=64, 8 waves, 8-PHASE schedule -----
// R13 = R12 geometry (same tiles, swizzle, LDS, math order -> bitwise-equal
// output) with the T3+T4 counted-vmcnt 4-phase/K-tile schedule replacing the
// 2-phase stage-all/compute-all/__syncthreads loop (m233: 2ph critical path
// = stage+vmcnt0+barrier ~72%; m218: counted-vs-drain0 = +38..73%).
//
// Staging order per K-tile t+1 (8 gload_lds/thread, into buf c^1), matching
// consumption order of tile t+1's phases:
//   phase0 of t: B01   phase1: B23   phase2: A02   phase3: A13
// (A chunk j = rows [j*64,j*64+64). Wave (wm,wn) phase p consumes
//  A rows wm*128+p*32..+31 -> chunk 2*wm+(p>>1); B rows wn*64.. = chunk wn.)
// Waits (per-wave FIFO audit; vmcnt counts own outstanding loads in order):
//  W1 (tile boundary): need B0-3,A0,A2 of next tile; outstanding = its 8
//     loads -> allow 2 newest (A1,A3) -> vmcnt(2); s_barrier publishes all
//     waves' contributions.
//  W2 (before phase2): need A1,A3 of current tile; outstanding = those 2 +
//     4 B-loads of next tile issued in phases 0-1 -> vmcnt(4).
//  Last tile (no staging): W2 -> vmcnt(0); no W1.
// WAR: stages into buf b start at phase0 of the tile AFTER the boundary
// barrier that ends all reads of buf b (read tile ended 1 tile earlier).
// Raw s_barrier + asm("":::"memory") fences (NOT __syncthreads) so the
// compiler cannot insert a vmcnt(0) drain.
__global__ __launch_bounds__(512, 2) void k_gemm3(
    const u16* __restrict__ A, const u16* __restrict__ Bt,
    const float* __restrict__ b0, const float* __restrict__ b1,
    const float* __restrict__ b2,
    u16* __restrict__ oq, u16* __restrict__ ok, u16* __restrict__ ov) {
  __shared__ __align__(16) u16 As[2][256][64];  // 64 KB
  __shared__ __align__(16) u16 Bs[2][256][64];  // 64 KB
  const int K = DM;
  int tid = threadIdx.x;
  int wave = tid >> 6, lane = tid & 63, quad = lane >> 4, l16 = lane & 15;
  int wr = wave >> 2, wc = wave & 3;
  int bm = blockIdx.x * 256, bn = blockIdx.y * 256;

  f32x4 acc[8][4] = {};

  // ---- staging addresses (source carries the XOR swizzle) ----
  int srow = wave * 8 + (lane >> 3);               // 0..63 (+ chunk*64)
  int scol = ((lane & 7) ^ (lane >> 3)) * 8;       // swizzled source col
  const u16* ga = A + (size_t)(bm + srow) * K + scol;
  const u16* gb = Bt + (size_t)(bn + srow) * K + scol;
  u16* aw0 = &As[0][wave * 8][0];
  u16* aw1 = &As[1][wave * 8][0];
  u16* bw0 = &Bs[0][wave * 8][0];
  u16* bw1 = &Bs[1][wave * 8][0];

  // ---- read-side frag base pointers (phys block = logical ^ (row&7)) ----
  int e7 = l16 & 7;
  const u16* aP00 = &As[0][wr * 128 + l16][0] + ((quad) ^ e7) * 8;
  const u16* aP01 = &As[0][wr * 128 + l16][0] + ((4 + quad) ^ e7) * 8;
  const u16* aP10 = &As[1][wr * 128 + l16][0] + ((quad) ^ e7) * 8;
  const u16* aP11 = &As[1][wr * 128 + l16][0] + ((4 + quad) ^ e7) * 8;
  const u16* bP00 = &Bs[0][wc * 64 + l16][0] + ((quad) ^ e7) * 8;
  const u16* bP01 = &Bs[0][wc * 64 + l16][0] + ((4 + quad) ^ e7) * 8;
  const u16* bP10 = &Bs[1][wc * 64 + l16][0] + ((quad) ^ e7) * 8;
  const u16* bP11 = &Bs[1][wc * 64 + l16][0] + ((4 + quad) ^ e7) * 8;

#define SBAR()                            \
  {                                       \
    asm volatile("" ::: "memory");        \
    __builtin_amdgcn_s_barrier();         \
    asm volatile("" ::: "memory");        \
  }

#define GLD(gp, lp)                                                \
  __builtin_amdgcn_global_load_lds(                                \
      (const __attribute__((address_space(1))) void*)(gp),         \
      (__attribute__((address_space(3))) void*)(lp), 16, 0, 0)

#define STG_B01(TI, NB)                                            \
  {                                                                \
    GLD(gb + (size_t)(TI) * 64, bw##NB);                           \
    GLD(gb + (size_t)64 * K + (size_t)(TI) * 64, bw##NB + 4096);   \
  }
#define STG_B23(TI, NB)                                            \
  {                                                                \
    GLD(gb + (size_t)128 * K + (size_t)(TI) * 64, bw##NB + 8192);  \
    GLD(gb + (size_t)192 * K + (size_t)(TI) * 64, bw##NB + 12288); \
  }
#define STG_A02(TI, NB)                                            \
  {                                                                \
    GLD(ga + (size_t)(TI) * 64, aw##NB);                           \
    GLD(ga + (size_t)128 * K + (size_t)(TI) * 64, aw##NB + 8192);  \
  }
#define STG_A13(TI, NB)                                            \
  {                                                                \
    GLD(ga + (size_t)64 * K + (size_t)(TI) * 64, aw##NB + 4096);   \
    GLD(ga + (size_t)192 * K + (size_t)(TI) * 64, aw##NB + 12288); \
  }

#define MM2(M0, M1)                                                \
  _Pragma("unroll") for (int n = 0; n < 4; ++n) {                  \
    acc[M0][n] = MFMA16(afA0, bfr[n][0], acc[M0][n]);              \
    acc[M0][n] = MFMA16(afA1, bfr[n][1], acc[M0][n]);              \
    acc[M1][n] = MFMA16(afB0, bfr[n][0], acc[M1][n]);              \
    acc[M1][n] = MFMA16(afB1, bfr[n][1], acc[M1][n]);              \
  }

// one K-tile: 4 phases, each {ds_read subtile; stage issue; SBAR; MFMA; SBAR}
#define TILE(T, BUF, NB, DOSTAGE)                                             \
  {                                                                           \
    /* phase 0: all B frags + A m0,m1 ; stage B01(T+1) */                     \
    bf16x8 bfr[4][2];                                                         \
    _Pragma("unroll") for (int n = 0; n < 4; ++n) {                           \
      bfr[n][0] = *(const bf16x8*)(bP##BUF##0 + n * 1024);                    \
      bfr[n][1] = *(const bf16x8*)(bP##BUF##1 + n * 1024);                    \
    }                                                                         \
    bf16x8 afA0 = *(const bf16x8*)(aP##BUF##0 + 0 * 1024);                    \
    bf16x8 afA1 = *(const bf16x8*)(aP##BUF##1 + 0 * 1024);                    \
    bf16x8 afB0 = *(const bf16x8*)(aP##BUF##0 + 1 * 1024);                    \
    bf16x8 afB1 = *(const bf16x8*)(aP##BUF##1 + 1 * 1024);                    \
    if (DOSTAGE) STG_B01((T) + 1, NB);                                        \
    SBAR();                                                                   \
    __builtin_amdgcn_s_setprio(1);                                            \
    MM2(0, 1);                                                                \
    __builtin_amdgcn_s_setprio(0);                                            \
    SBAR();                                                                   \
    /* phase 1: A m2,m3 ; stage B23 ; end: W2 */                              \
    afA0 = *(const bf16x8*)(aP##BUF##0 + 2 * 1024);                           \
    afA1 = *(const bf16x8*)(aP##BUF##1 + 2 * 1024);                           \
    afB0 = *(const bf16x8*)(aP##BUF##0 + 3 * 1024);                           \
    afB1 = *(const bf16x8*)(aP##BUF##1 + 3 * 1024);                           \
    if (DOSTAGE) STG_B23((T) + 1, NB);                                        \
    SBAR();                                                                   \
    __builtin_amdgcn_s_setprio(1);                                            \
    MM2(2, 3);                                                                \
    __builtin_amdgcn_s_setprio(0);                                            \
    if (DOSTAGE) {                                                            \
      asm volatile("s_waitcnt vmcnt(4)" ::: "memory");                        \
    } else {                                                                  \
      asm volatile("s_waitcnt vmcnt(0)" ::: "memory");                        \
    }                                                                         \
    SBAR();                                                                   \
    /* phase 2: A m4,m5 ; stage A02 */                                        \
    afA0 = *(const bf16x8*)(aP##BUF##0 + 4 * 1024);                           \
    afA1 = *(const bf16x8*)(aP##BUF##1 + 4 * 1024);                           \
    afB0 = *(const bf16x8*)(aP##BUF##0 + 5 * 1024);                           \
    afB1 = *(const bf16x8*)(aP##BUF##1 + 5 * 1024);                           \
    if (DOSTAGE) STG_A02((T) + 1, NB);                                        \
    SBAR();                                                                   \
    __builtin_amdgcn_s_setprio(1);                                            \
    MM2(4, 5);                                                                \
    __builtin_amdgcn_s_setprio(0);                                            \
    SBAR();                                                                   \
    /* phase 3: A m6,m7 ; stage A13 ; end: W1 */                              \
    afA0 = *(const bf16x8*)(aP##BUF##0 + 6 * 1024);                           \
    afA1 = *(const bf16x8*)(aP##BUF##1 + 6 * 1024);                           \
    afB0 = *(const bf16x8*)(aP##BUF##0 + 7 * 1024);                           \
    afB1 = *(const bf16x8*)(aP##BUF##1 + 7 * 1024);                           \
    if (DOSTAGE) STG_A13((T) + 1, NB);                                        \
    SBAR();                                                                   \
    __builtin_amdgcn_s_setprio(1);                                            \
    MM2(6, 7);                                                                \
    __builtin_amdgcn_s_setprio(0);                                            \
    if (DOSTAGE) {                                                            \
      asm volatile("s_waitcnt vmcnt(2)" ::: "memory");                        \
    }                                                                         \
    SBAR();                                                                   \
  }

  // ---- prologue: stage tile 0 -> buf0, W1, barrier ----
  STG_B01(0, 0);
  STG_B23(0, 0);
  STG_A02(0, 0);
  STG_A13(0, 0);
  asm volatile("s_waitcnt vmcnt(2)" ::: "memory");
  SBAR();

#pragma unroll 1
  for (int tt = 0; tt < 7; ++tt) {
    int t0 = tt * 2;
    TILE(t0, 0, 1, 1);
    TILE(t0 + 1, 1, 0, 1);
  }
  TILE(14, 0, 1, 1);
  TILE(15, 1, 0, 0);

#undef TILE
#undef MM2
#undef STG_A13
#undef STG_A02
#undef STG_B23
#undef STG_B01
#undef GLD
#undef SBAR

  // ---- epilogue: bias + QKV scatter (BN=256 divides the 1024 segments) ---
  int seg = bn >> 10;
  const float* bia = seg == 0 ? b0 : seg == 1 ? b1 : b2;
  int cb = bn & 1023;
  if (seg == 2) {
#pragma unroll
    for (int m = 0; m < 8; ++m)
#pragma unroll
      for (int n = 0; n < 4; ++n) {
        int row = bm + wr * 128 + m * 16 + quad * 4;
        int col = cb + wc * 64 + n * 16 + l16;
        float bv_ = bia[col];
        int bb2 = row >> 11, s = row & 2047, hh = col >> 6, dh = col & 63;
        ushort4 o4;
        o4.x = f2bf(acc[m][n][0] + bv_);
        o4.y = f2bf(acc[m][n][1] + bv_);
        o4.z = f2bf(acc[m][n][2] + bv_);
        o4.w = f2bf(acc[m][n][3] + bv_);
        *(ushort4*)(&ov[(((size_t)bb2 * NH + hh) * DH + dh) * SS + s]) = o4;
      }
  } else {
    u16* o = seg == 0 ? oq : ok;
    float sc = seg == 0 ? (0.125f * 1.44269504f) : 1.0f;
#pragma unroll
    for (int m = 0; m < 8; ++m)
#pragma unroll
      for (int n = 0; n < 4; ++n)
#pragma unroll
        for (int r = 0; r < 4; ++r) {
          int row = bm + wr * 128 + m * 16 + quad * 4 + r;
          int col = cb + wc * 64 + n * 16 + l16;
          float v = (acc[m][n][r] + bia[col]) * sc;
          int bb2 = row >> 11, s = row & 2047, hh = col >> 6, dh = col & 63;
          o[((((size_t)bb2 * NH + hh) * SS) + s) * DH + dh] = f2bf(v);
        }
  }
}

// ---------------- flash attention (R0-exact: the 105us best) --------------
// grid: (S/128, NH, BB), block 256 (4 waves, 32 q-rows each)
__global__ __launch_bounds__(256) void k_attn(const u16* __restrict__ Q,
                                              const u16* __restrict__ Kg,
                                              const u16* __restrict__ VT,
                                              u16* __restrict__ ctx) {
  __shared__ __align__(16) u16 Ks[2][64][64];
  __shared__ __align__(16) u16 Vts[2][64][64];  // [d][kv], swizzled
  int tid = threadIdx.x;
  int wave = tid >> 6, lane = tid & 63, quad = lane >> 4, l16 = lane & 15;
  int q0 = blockIdx.x * 128;
  int h = blockIdx.y, b = blockIdx.z;
  size_t bh = ((size_t)b * NH + h) * SS * DH;
  const u16* Qp = Q + bh + (size_t)(q0 + wave * 32) * DH;
  const u16* Kp = Kg + bh;
  const u16* Vp = VT + ((size_t)b * NH + h) * DH * SS;  // [Dh][S]

  // Q as B-operand fragments: B[k=d=quad*8+j][n=q=l16], 2 q-tiles
  bf16x8 qf[2][2];
#pragma unroll
  for (int qt = 0; qt < 2; ++qt) {
    qf[qt][0] = ld_bf8(Qp + (qt * 16 + l16) * DH + quad * 8);
    qf[qt][1] = ld_bf8(Qp + (qt * 16 + l16) * DH + 32 + quad * 8);
  }

  f32x4 Ot[4][2] = {};           // [d-tile][q-tile], O^T C-layout
  float lrun[2] = {0.0f, 0.0f};  // per-lane partial sums (q = l16)

  // ---- staging constants (global side carries the swizzle) ----
  int lrow = lane >> 3;            // 0..7 (row within 8-row DMA chunk)
  int lcb = (lane & 7) ^ lrow;     // swizzled global col-block
  const u16* kdma[2];
  const u16* vdma[2];
  u16* kl[2];
  u16* vl[2];
#pragma unroll
  for (int i = 0; i < 2; ++i) {
    int chunk = wave * 2 + i;      // 0..7, 8 rows each
    kdma[i] = Kp + (size_t)(chunk * 8 + lrow) * DH + lcb * 8;
    vdma[i] = Vp + (size_t)(chunk * 8 + lrow) * SS + lcb * 8;
    kl[i] = &Ks[0][chunk * 8][0];
    vl[i] = &Vts[0][chunk * 8][0];
  }

  // ---- hoisted frag pointers (loop addressing = base + literal) ----
  int e7 = l16 & 7, qh = quad >> 1, qp = quad & 1;
  const u16* kfr0 = &Ks[0][l16][(quad ^ e7) * 8];        // d-blocks 0..3
  const u16* kfr1 = &Ks[0][l16][((quad + 4) ^ e7) * 8];  // d-blocks 4..7
  const u16* vfr[4];
#pragma unroll
  for (int c = 0; c < 4; ++c)
    vfr[c] = &Vts[0][l16][((2 * c + qh) ^ e7) * 8 + qp * 4];

  // ---- prestage tile kv=0 into buffer 0 ----
#pragma unroll
  for (int i = 0; i < 2; ++i) {
    __builtin_amdgcn_global_load_lds(
        (const __attribute__((address_space(1))) void*)kdma[i],
        (__attribute__((address_space(3))) void*)kl[i], 16, 0, 0);
    __builtin_amdgcn_global_load_lds(
        (const __attribute__((address_space(1))) void*)vdma[i],
        (__attribute__((address_space(3))) void*)vl[i], 16, 0, 0);
  }
  __syncthreads();

  int kv = 64;  // next tile to stage

#define ATTN_STEP(P)                                                          \
  {                                                                           \
    f32x4 s[2][4];                                                            \
    _Pragma("unroll") for (int t = 0; t < 4; ++t) {                           \
      bf16x8 kb0 = *(const bf16x8*)(kfr0 + (P) * 4096 + t * 1024);            \
      bf16x8 kb1 = *(const bf16x8*)(kfr1 + (P) * 4096 + t * 1024);            \
      _Pragma("unroll") for (int qt = 0; qt < 2; ++qt) {                      \
        f32x4 z = {};                                                         \
        z = MFMA16(kb0, qf[qt][0], z);                                        \
        z = MFMA16(kb1, qf[qt][1], z);                                        \
        s[qt][t] = z;                                                         \
      }                                                                       \
    }                                                                         \
    if (kv < SS) {                                                            \
      _Pragma("unroll") for (int i = 0; i < 2; ++i) {                         \
        __builtin_amdgcn_global_load_lds(                                     \
            (const __attribute__((address_space(1))) void*)(kdma[i] +         \
                                                            (size_t)kv * DH), \
            (__attribute__((address_space(3))) void*)(kl[i] +                 \
                                                      (1 - (P)) * 4096),      \
            16, 0, 0);                                                        \
        __builtin_amdgcn_global_load_lds(                                     \
            (const __attribute__((address_space(1))) void*)(vdma[i] + kv),    \
            (__attribute__((address_space(3))) void*)(vl[i] +                 \
                                                      (1 - (P)) * 4096),      \
            16, 0, 0);                                                        \
      }                                                                       \
    }                                                                         \
    bf16x4 pb[2][4];                                                          \
    _Pragma("unroll") for (int qt = 0; qt < 2; ++qt)                          \
        _Pragma("unroll") for (int t = 0; t < 4; ++t) {                       \
      unsigned u0 = __builtin_bit_cast(                                       \
          unsigned, __builtin_amdgcn_exp2f(s[qt][t][0]));                     \
      unsigned u1 = __builtin_bit_cast(                                       \
          unsigned, __builtin_amdgcn_exp2f(s[qt][t][1]));                     \
      unsigned u2 = __builtin_bit_cast(                                       \
          unsigned, __builtin_amdgcn_exp2f(s[qt][t][2]));                     \
      unsigned u3 = __builtin_bit_cast(                                       \
          unsigned, __builtin_amdgcn_exp2f(s[qt][t][3]));                     \
      unsigned w0 = __builtin_amdgcn_perm(u1, u0, 0x07060302u);               \
      unsigned w1 = __builtin_amdgcn_perm(u3, u2, 0x07060302u);               \
      lrun[qt] += __builtin_bit_cast(float, w0 << 16) +                       \
                  __builtin_bit_cast(float, w0 & 0xffff0000u) +               \
                  __builtin_bit_cast(float, w1 << 16) +                       \
                  __builtin_bit_cast(float, w1 & 0xffff0000u);                \
      uintx2 w;                                                               \
      w[0] = w0;                                                              \
      w[1] = w1;                                                              \
      pb[qt][t] = __builtin_bit_cast(bf16x4, w);                              \
    }                                                                         \
    _Pragma("unroll") for (int c = 0; c < 4; ++c)                             \
        _Pragma("unroll") for (int dt = 0; dt < 4; ++dt) {                    \
      bf16x4 va = *(const bf16x4*)(vfr[c] + (P) * 4096 + dt * 1024);          \
      _Pragma("unroll") for (int qt = 0; qt < 2; ++qt)                        \
          Ot[dt][qt] = MFMA16K16(va, pb[qt][c], Ot[dt][qt]);                  \
    }                                                                         \
    __syncthreads();                                                          \
    kv += 64;                                                                 \
  }

  for (int it = 0; it < SS / 128; ++it) {
    ATTN_STEP(0);
    ATTN_STEP(1);
  }
#undef ATTN_STEP

  // final normalizer: lanes {l16, +16, +32, +48} hold q=l16 partials
  float inv[2];
#pragma unroll
  for (int qt = 0; qt < 2; ++qt) {
    float l = lrun[qt];
    l += __shfl_xor(l, 16);
    l += __shfl_xor(l, 32);
    inv[qt] = 1.0f / l;
  }

  // write O^T: per lane q = l16 (fixed), d = dt*16 + quad*4 + r (contiguous)
#pragma unroll
  for (int qt = 0; qt < 2; ++qt) {
    int q = q0 + wave * 32 + qt * 16 + l16;
    size_t ob = ((size_t)b * SS + q) * DM + h * DH;
#pragma unroll
    for (int dt = 0; dt < 4; ++dt) {
      uintx2 o;
      o[0] = pack2bf(Ot[dt][qt][0] * inv[qt], Ot[dt][qt][1] * inv[qt]);
      o[1] = pack2bf(Ot[dt][qt][2] * inv[qt], Ot[dt][qt][3] * inv[qt]);
      *(uintx2*)(&ctx[ob + dt * 16 + quad * 4]) = o;
    }
  }
}

extern "C" void kernel_launch(void* const* d_in, const int* in_sizes, int n_in,
                              void* d_out, int out_size, void* d_ws, size_t ws_size,
                              hipStream_t stream) {
  const float* x  = (const float*)d_in[0];
  const float* Wq = (const float*)d_in[1];
  const float* bq = (const float*)d_in[2];
  const float* Wk = (const float*)d_in[3];
  const float* bk = (const float*)d_in[4];
  const float* Wv = (const float*)d_in[5];
  const float* bv = (const float*)d_in[6];
  const float* Wo = (const float*)d_in[7];
  const float* bo = (const float*)d_in[8];
  float* out = (float*)d_out;

  char* ws = (char*)d_ws;
  u16* xb = (u16*)(ws);                        // 16 MB  [8192,1024] bf16
  u16* Wt = (u16*)(ws + (16u << 20));          //  8 MB  [4096,1024] bf16
  u16* Qb = (u16*)(ws + (24u << 20));          // 16 MB  [B,H,S,Dh] (pre-scaled)
  u16* Kb = (u16*)(ws + (40u << 20));          // 16 MB  [B,H,S,Dh]
  u16* VT = (u16*)(ws + (56u << 20));          // 16 MB  [B,H,Dh,S]
  u16* Cb = (u16*)(ws + (72u << 20));          // 16 MB  [B,S,D] bf16 ctx

  k_cvt_x<<<MROWS * DM / 1024, 256, 0, stream>>>(x, xb);
  k_tw<<<dim3(32, 128), dim3(32, 32), 0, stream>>>(Wq, Wk, Wv, Wo, Wt);
  k_gemm3<<<dim3(MROWS / 256, 12), 512, 0, stream>>>(
      xb, Wt, bq, bk, bv, Qb, Kb, VT);
  k_attn<<<dim3(SS / 128, NH, BB), 256, 0, stream>>>(Qb, Kb, VT, Cb);
  k_gemm<<<dim3(MROWS / 128, 8), 256, 0, stream>>>(
      Cb, Wt + (size_t)3 * DM * DM, MROWS, DM, DM, bo, out);
}